// Round 16
// baseline (12936.427 us; speedup 1.0000x reference)
//
#include <hip/hip_runtime.h>
#include <hip/hip_cooperative_groups.h>
#include <math.h>

#define BATCH 32
#define LEN   160000
#define NFFT  512
#define NT    626
#define NF    257
#define NFP   288          // NF padded to 9*32
#define HID   512
#define PROJN 5140
#define TC    32
#define NCHUNK 20
#define K0    800          // NFP + HID
#define K1    1024         // HID + HID
#define NLSTM 64           // LSTM blocks
#define NWORK 192          // worker blocks
#define NBLKT 256          // total blocks

typedef unsigned short ushort;
typedef __attribute__((ext_vector_type(8))) short short8;
typedef __attribute__((ext_vector_type(4))) float f32x4;

__device__ __forceinline__ float sigm(float x){ return 1.0f/(1.0f+expf(-x)); }
__device__ __forceinline__ ushort f2bf(float f){
  union{float f;unsigned u;} v; v.f=f;
  unsigned r = v.u + 0x7fffu + ((v.u>>16)&1u);
  return (ushort)(r>>16);
}

// ---------------- merged setup ----------------
__global__ __launch_bounds__(256) void k_setup(float* tw, int* zr, int nz,
                                               float* h1slot0, int nh1s,
                                               float* outz, int nout,
                                               const float* __restrict__ Wih0, const float* __restrict__ Whh0,
                                               const float* __restrict__ bih0, const float* __restrict__ bhh0,
                                               const float* __restrict__ Wih1, const float* __restrict__ Whh1,
                                               const float* __restrict__ bih1, const float* __restrict__ bhh1,
                                               const float* __restrict__ projW,
                                               ushort* __restrict__ W0, ushort* __restrict__ W1,
                                               float* __restrict__ b0c, float* __restrict__ b1c,
                                               ushort* __restrict__ projWb){
  const int gsz = gridDim.x*256;
  int gid = blockIdx.x*256 + threadIdx.x;
  if (gid < 512){
    float ang = 6.28318530717958647692f * (float)gid / 512.0f;
    tw[gid]     = cosf(ang);
    tw[512+gid] = sinf(ang);
  }
  for (int j = gid; j < nz; j += gsz) zr[j] = 0;
  for (int j = gid; j < nh1s; j += gsz) h1slot0[j] = 0.f;
  for (int j = gid; j < nout; j += gsz) outz[j] = 0.f;
  const int n0 = 2048*K0, n1 = 2048*K1, n2 = PROJN*HID;
  for (int i = gid; i < n0 + n1 + 4096 + n2; i += gsz){
    if (i < n0){
      int r = i / K0, c = i - r*K0;
      float v = (c < 257) ? Wih0[(size_t)r*257 + c] : (c < NFP ? 0.f : Whh0[(size_t)r*512 + (c-NFP)]);
      W0[i] = f2bf(v);
    } else if (i < n0 + n1){
      int j = i - n0;
      int r = j / K1, c = j - r*K1;
      float v = (c < 512) ? Wih1[(size_t)r*512 + c] : Whh1[(size_t)r*512 + (c-512)];
      W1[j] = f2bf(v);
    } else if (i < n0 + n1 + 4096){
      int j = i - n0 - n1;
      if (j < 2048) b0c[j] = bih0[j] + bhh0[j];
      else          b1c[j-2048] = bih1[j-2048] + bhh1[j-2048];
    } else {
      int j = i - n0 - n1 - 4096;
      projWb[j] = f2bf(projW[j]);
    }
  }
}

// ---------------- fused STFT + mag^0.5 + LayerNorm ----------------
__global__ __launch_bounds__(256) void k_stftln(const float* __restrict__ x, const float* __restrict__ tw,
                                                const float* __restrict__ g, const float* __restrict__ be,
                                                ushort* __restrict__ hlnb){
  int b = blockIdx.x / NT;
  int t = blockIdx.x % NT;
  __shared__ float fr[NFFT], mg[NF];
  __shared__ float red[16];
  const float* xb = x + (size_t)b*LEN;
  for (int n = threadIdx.x; n < NFFT; n += 256){
    int j = t*256 + n - 256;
    if (j < 0) j = -j;
    else if (j >= LEN) j = 2*LEN - 2 - j;
    fr[n] = xb[j] * (0.5f - 0.5f*tw[n]);
  }
  __syncthreads();
  float v=0.f, v2=0.f;
  for (int f = threadIdx.x; f < NF; f += 256){
    float c4 = tw[(4*f)&511], s4 = tw[512+((4*f)&511)];
    float cr0=1.f,            si0=0.f;
    float cr1=tw[f&511],      si1=tw[512+(f&511)];
    float cr2=tw[(2*f)&511],  si2=tw[512+((2*f)&511)];
    float cr3=tw[(3*f)&511],  si3=tw[512+((3*f)&511)];
    float ar0=0.f,ai0=0.f,ar1=0.f,ai1=0.f,ar2=0.f,ai2=0.f,ar3=0.f,ai3=0.f;
    #pragma unroll 4
    for (int n = 0; n < NFFT; n += 4){
      ar0 += fr[n  ]*cr0; ai0 -= fr[n  ]*si0;
      ar1 += fr[n+1]*cr1; ai1 -= fr[n+1]*si1;
      ar2 += fr[n+2]*cr2; ai2 -= fr[n+2]*si2;
      ar3 += fr[n+3]*cr3; ai3 -= fr[n+3]*si3;
      float tc, ts;
      tc = cr0*c4 - si0*s4; ts = cr0*s4 + si0*c4; cr0=tc; si0=ts;
      tc = cr1*c4 - si1*s4; ts = cr1*s4 + si1*c4; cr1=tc; si1=ts;
      tc = cr2*c4 - si2*s4; ts = cr2*s4 + si2*c4; cr2=tc; si2=ts;
      tc = cr3*c4 - si3*s4; ts = cr3*s4 + si3*c4; cr3=tc; si3=ts;
    }
    float ar = (ar0+ar1)+(ar2+ar3);
    float ai = (ai0+ai1)+(ai2+ai3);
    float m = sqrtf(sqrtf(ar*ar + ai*ai));
    mg[f]=m; v+=m; v2+=m*m;
  }
  for (int off=32; off; off>>=1){ v += __shfl_down(v,off); v2 += __shfl_down(v2,off); }
  int w = threadIdx.x >> 6;
  if ((threadIdx.x & 63)==0){ red[w]=v; red[8+w]=v2; }
  __syncthreads();
  if (threadIdx.x==0){
    float s  = red[0]+red[1]+red[2]+red[3];
    float s2 = red[8]+red[9]+red[10]+red[11];
    float mu = s/(float)NF;
    red[4]=mu;
    red[5]=rsqrtf(s2/(float)NF - mu*mu + 1e-5f);
  }
  __syncthreads();
  float mu=red[4], rs=red[5];
  size_t ob = ((size_t)t*BATCH + b)*NFP;
  for (int f=threadIdx.x; f<NFP; f+=256){
    float val = 0.f;
    if (f < NF) val = (mg[f]-mu)*rs*g[f] + be[f];
    hlnb[ob+f] = f2bf(val);
  }
}

// ================= worker device functions =================
__device__ void dev_stft_frame(const float* __restrict__ x, const float* __restrict__ tw,
                               float* __restrict__ spR, float* __restrict__ spI,
                               int tb0, int tt, int b, float* fr){
  int t = tb0 + tt;
  int tid = threadIdx.x;
  if (t < 0 || t >= NT){
    for (int f = tid; f < NF; f += 256){
      size_t o = ((size_t)b*NF + f)*36 + tt;
      spR[o]=0.f; spI[o]=0.f;
    }
    return;
  }
  const float* xb = x + (size_t)b*LEN;
  for (int n = tid; n < NFFT; n += 256){
    int j = t*256 + n - 256;
    if (j < 0) j = -j;
    else if (j >= LEN) j = 2*LEN - 2 - j;
    fr[n] = xb[j] * (0.5f - 0.5f*tw[n]);
  }
  __syncthreads();
  for (int f = tid; f < NF; f += 256){
    float c4 = tw[(4*f)&511], s4 = tw[512+((4*f)&511)];
    float cr0=1.f,            si0=0.f;
    float cr1=tw[f&511],      si1=tw[512+(f&511)];
    float cr2=tw[(2*f)&511],  si2=tw[512+((2*f)&511)];
    float cr3=tw[(3*f)&511],  si3=tw[512+((3*f)&511)];
    float ar0=0.f,ai0=0.f,ar1=0.f,ai1=0.f,ar2=0.f,ai2=0.f,ar3=0.f,ai3=0.f;
    #pragma unroll 4
    for (int n = 0; n < NFFT; n += 4){
      ar0 += fr[n  ]*cr0; ai0 -= fr[n  ]*si0;
      ar1 += fr[n+1]*cr1; ai1 -= fr[n+1]*si1;
      ar2 += fr[n+2]*cr2; ai2 -= fr[n+2]*si2;
      ar3 += fr[n+3]*cr3; ai3 -= fr[n+3]*si3;
      float tc, ts;
      tc = cr0*c4 - si0*s4; ts = cr0*s4 + si0*c4; cr0=tc; si0=ts;
      tc = cr1*c4 - si1*s4; ts = cr1*s4 + si1*c4; cr1=tc; si1=ts;
      tc = cr2*c4 - si2*s4; ts = cr2*s4 + si2*c4; cr2=tc; si2=ts;
      tc = cr3*c4 - si3*s4; ts = cr3*s4 + si3*c4; cr3=tc; si3=ts;
    }
    size_t o = ((size_t)b*NF + f)*36 + tt;
    spR[o] = (ar0+ar1)+(ar2+ar3);
    spI[o] = (ai0+ai1)+(ai2+ai3);
  }
  __syncthreads();
}

__device__ void dev_gemm_tile(const ushort* __restrict__ A, const ushort* __restrict__ Bb,
                              const float* __restrict__ bias, float* __restrict__ C,
                              int M, int N, int bx, int by){
  int bm = by*64, bn = bx*64;
  int wave = threadIdx.x >> 6, lane = threadIdx.x & 63;
  int wm = wave >> 1, wn = wave & 1;
  int col = lane & 15, kg = lane >> 4;
  f32x4 acc00={0.f,0.f,0.f,0.f}, acc01=acc00, acc10=acc00, acc11=acc00;
  const ushort* Ap = A + (size_t)(bm + wm*32)*512;
  int nr0 = bn + wn*32 + col;
  int nr1 = nr0 + 16;
  const ushort* Bp0 = Bb + (size_t)((nr0<N)?nr0:0)*512;
  const ushort* Bp1 = Bb + (size_t)((nr1<N)?nr1:0)*512;
  #pragma unroll 4
  for (int k0=0; k0<512; k0+=32){
    short8 a0 = *(const short8*)(Ap + (size_t)col*512 + k0 + kg*8);
    short8 a1 = *(const short8*)(Ap + (size_t)(16+col)*512 + k0 + kg*8);
    short8 b0 = *(const short8*)(Bp0 + k0 + kg*8);
    short8 b1 = *(const short8*)(Bp1 + k0 + kg*8);
    acc00 = __builtin_amdgcn_mfma_f32_16x16x32_bf16(a0, b0, acc00, 0, 0, 0);
    acc01 = __builtin_amdgcn_mfma_f32_16x16x32_bf16(a0, b1, acc01, 0, 0, 0);
    acc10 = __builtin_amdgcn_mfma_f32_16x16x32_bf16(a1, b0, acc10, 0, 0, 0);
    acc11 = __builtin_amdgcn_mfma_f32_16x16x32_bf16(a1, b1, acc11, 0, 0, 0);
  }
  #define STORE_ACC(ACC, MI, NI) { \
    int n = bn + wn*32 + (NI)*16 + col; \
    if (n < N){ \
      float bv = bias[n]; \
      _Pragma("unroll") \
      for (int j=0;j<4;j++){ \
        int m = bm + wm*32 + (MI)*16 + kg*4 + j; \
        C[(size_t)m*N + n] = tanhf(ACC[j] + bv); \
      } \
    } }
  STORE_ACC(acc00, 0, 0)
  STORE_ACC(acc01, 0, 1)
  STORE_ACC(acc10, 1, 0)
  STORE_ACC(acc11, 1, 1)
  #undef STORE_ACC
}

__device__ void dev_ifused_task(const float* __restrict__ prch,
    const float* __restrict__ spR, const float* __restrict__ spI,
    const float* __restrict__ tw, float* __restrict__ out, int tb0, int task,
    float* reb, float* imb){
  int tl = task >> 6;
  int b  = (task >> 1) & 31;
  int s  = task & 1;
  int tau = tb0 + 4 + tl;
  int tid = threadIdx.x;
  const float* p = prch + ((size_t)tl*BATCH + b)*PROJN;
  for (int f=tid; f<NF; f+=256){
    float ar=0.f, ai=0.f;
    size_t so = ((size_t)b*NF + f)*36;
    #pragma unroll
    for (int d=0; d<5; d++){
      int ts = tb0 + tl + d;
      if (ts >= 0){
        float sr=spR[so + tl + d], si=spI[so + tl + d];
        float cr=p[d*514 + s*257 + f];
        float ci=p[2570 + d*514 + s*257 + f];
        ar += sr*cr - si*ci;
        ai += sr*ci + si*cr;
      }
    }
    reb[f]=ar; imb[f]=ai;
  }
  __syncthreads();
  float* ob = out + (size_t)(b*2+s)*LEN;
  for (int n=tid; n<NFFT; n+=256){
    float c4 = tw[(4*n)&511], s4 = tw[512+((4*n)&511)];
    float crA=tw[n&511],     siA=tw[512+(n&511)];
    float crB=tw[(2*n)&511], siB=tw[512+((2*n)&511)];
    float crC=tw[(3*n)&511], siC=tw[512+((3*n)&511)];
    float crD=c4,            siD=s4;
    float a0=0.f,a1=0.f,a2=0.f,a3=0.f;
    #pragma unroll 4
    for (int m=0; m<63; m++){
      int k = 4*m+1;
      a0 += reb[k  ]*crA - imb[k  ]*siA;
      a1 += reb[k+1]*crB - imb[k+1]*siB;
      a2 += reb[k+2]*crC - imb[k+2]*siC;
      a3 += reb[k+3]*crD - imb[k+3]*siD;
      float tc, ts;
      tc = crA*c4 - siA*s4; ts = crA*s4 + siA*c4; crA=tc; siA=ts;
      tc = crB*c4 - siB*s4; ts = crB*s4 + siB*c4; crB=tc; siB=ts;
      tc = crC*c4 - siC*s4; ts = crC*s4 + siC*c4; crC=tc; siC=ts;
      tc = crD*c4 - siD*s4; ts = crD*s4 + siD*c4; crD=tc; siD=ts;
    }
    a0 += reb[253]*crA - imb[253]*siA;
    a1 += reb[254]*crB - imb[254]*siB;
    a2 += reb[255]*crC - imb[255]*siC;
    float acc = reb[0] + ((n&1) ? -reb[256] : reb[256]) + 2.f*((a0+a1)+(a2+a3));
    int pos = tau*256 - 256 + n;
    if (pos >= 0 && pos < LEN)
      atomicAdd(ob + pos, acc * (1.0f/512.0f) * (0.5f - 0.5f*tw[n&511]));
  }
  __syncthreads();
}

// ================= persistent mega-kernel (r14 structure + XCD-concentrated LSTM roles) =================
// LSTM role: blocks with (bid&7)<2 (under round-robin bid->XCD mapping these sit on 2 XCDs).
// lbid = (bid>>3)*2 + (bid&7) in 0..63. Workers: remaining 192 blocks.
__global__ __launch_bounds__(256, 1) void k_mega(const ushort* __restrict__ hlnb,
    const ushort* __restrict__ W0g, const ushort* __restrict__ W1g,
    const float* __restrict__ b0c, const float* __restrict__ b1c,
    ushort* __restrict__ h0b, ushort* __restrict__ h1b, ushort* __restrict__ h1hist,
    unsigned* __restrict__ flagsA, unsigned* __restrict__ epoch, unsigned* __restrict__ done,
    const float* __restrict__ x, const float* __restrict__ tw,
    const ushort* __restrict__ projWb, const float* __restrict__ projb,
    float* __restrict__ spR, float* __restrict__ spI, float* __restrict__ prch,
    float* __restrict__ out){
  __shared__ ushort Wlds0[32*808];
  __shared__ ushort Wlds1[32*1032];
  __shared__ float pc0[32][33];
  __shared__ float pc1[32][33];
  __shared__ float fr[NFFT];
  __shared__ float reb[NF], imb[NF];

  const int tid  = threadIdx.x;
  const int bid  = blockIdx.x;
  const int r8   = bid & 7;

  if (r8 < 2){
    // ================= LSTM role (r6 canonical; lbid replaces bid) =================
    const int lbid = ((bid >> 3) << 1) + r8;         // 0..63
    const int u0   = lbid << 3;
    const int wave = tid >> 6;
    const int lane = tid & 63;
    const int col  = lane & 15;
    const int kg   = lane >> 4;
    const int mh   = wave & 1;
    const int nh   = wave >> 1;
    const int arow = (mh<<4) + col;
    const int nlo  = (nh<<4) + col;

    for (int v = tid; v < 3200; v += 256){
      int r = v/100, c8 = v - r*100;
      int grow = ((r>>3)<<9) + u0 + (r&7);
      *(short8*)&Wlds0[r*808 + c8*8] = *(const short8*)(W0g + (size_t)grow*K0 + c8*8);
    }
    for (int v = tid; v < 4096; v += 256){
      int r = v>>7, c8 = v&127;
      int grow = ((r>>3)<<9) + u0 + (r&7);
      *(short8*)&Wlds1[r*1032 + c8*8] = *(const short8*)(W1g + (size_t)grow*K1 + c8*8);
    }
    const int bb = tid & 31;
    const int ul = tid >> 5;
    const int u  = u0 + ul;
    float bc0r[4], bc1r[4];
    #pragma unroll
    for (int g=0; g<4; g++){ bc0r[g] = b0c[(g<<9)+u]; bc1r[g] = b1c[(g<<9)+u]; }
    float c0r = 0.f, c1r = 0.f;
    const ushort* wb0 = &Wlds0[nlo*808];
    const ushort* wb1 = &Wlds1[nlo*1032];
    __syncthreads();

    f32x4 acc0x = {0.f,0.f,0.f,0.f};
    {
      const ushort* xt = hlnb;
      #pragma unroll
      for (int kt=0; kt<9; kt++){
        short8 a = *(const short8*)(xt + arow*NFP + kt*32 + kg*8);
        short8 b = *(const short8*)(wb0 + kt*32 + kg*8);
        acc0x = __builtin_amdgcn_mfma_f32_16x16x32_bf16(a, b, acc0x, 0, 0, 0);
      }
    }

    for (int t = 0; t <= NT; ++t){
      const ushort* h0p = h0b + (size_t)((t-1)&1)*(BATCH*HID);
      f32x4 acc0 = acc0x;
      f32x4 acc1 = {0.f,0.f,0.f,0.f};
      if (t >= 1){
        const ushort* h1p = h1b + (size_t)((t-2)&1)*(BATCH*HID);
        #pragma unroll
        for (int kt=0; kt<16; kt++){
          short8 a = *(const short8*)(h0p + arow*HID + kt*32 + kg*8);
          short8 b = *(const short8*)(wb1 + kt*32 + kg*8);
          acc1 = __builtin_amdgcn_mfma_f32_16x16x32_bf16(a, b, acc1, 0, 0, 0);
        }
        #pragma unroll
        for (int kt=0; kt<16; kt++){
          short8 a = *(const short8*)(h1p + arow*HID + kt*32 + kg*8);
          short8 b = *(const short8*)(wb1 + 512 + kt*32 + kg*8);
          acc1 = __builtin_amdgcn_mfma_f32_16x16x32_bf16(a, b, acc1, 0, 0, 0);
        }
      }
      if (t < NT){
        #pragma unroll
        for (int kt=0; kt<16; kt++){
          short8 a = *(const short8*)(h0p + arow*HID + kt*32 + kg*8);
          short8 b = *(const short8*)(wb0 + 288 + kt*32 + kg*8);
          acc0 = __builtin_amdgcn_mfma_f32_16x16x32_bf16(a, b, acc0, 0, 0, 0);
        }
      }
      if (t < NT){
        #pragma unroll
        for (int j=0;j<4;j++) pc0[(mh<<4)+(kg<<2)+j][nlo] = acc0[j];
      }
      if (t >= 1){
        #pragma unroll
        for (int j=0;j<4;j++) pc1[(mh<<4)+(kg<<2)+j][nlo] = acc1[j];
      }
      __syncthreads();
      if (t < NT){
        float p0 = pc0[bb][0*8+ul] + bc0r[0];
        float p1 = pc0[bb][1*8+ul] + bc0r[1];
        float p2 = pc0[bb][2*8+ul] + bc0r[2];
        float p3 = pc0[bb][3*8+ul] + bc0r[3];
        float cn = sigm(p1)*c0r + sigm(p0)*tanhf(p2);
        float hn = sigm(p3)*tanhf(cn);
        c0r = cn;
        h0b[(size_t)(t&1)*(BATCH*HID) + bb*HID + u] = f2bf(hn);
      }
      if (t >= 1){
        float p0 = pc1[bb][0*8+ul] + bc1r[0];
        float p1 = pc1[bb][1*8+ul] + bc1r[1];
        float p2 = pc1[bb][2*8+ul] + bc1r[2];
        float p3 = pc1[bb][3*8+ul] + bc1r[3];
        float cn = sigm(p1)*c1r + sigm(p0)*tanhf(p2);
        float hn = sigm(p3)*tanhf(cn);
        c1r = cn;
        ushort hb = f2bf(hn);
        h1b[(size_t)((t-1)&1)*(BATCH*HID) + bb*HID + u] = hb;
        __builtin_nontemporal_store(hb, h1hist + (size_t)t*(BATCH*HID) + bb*HID + u);
      }
      __syncthreads();                     // drain stores (vmcnt0)
      if (tid == 0)
        __hip_atomic_store(&flagsA[lbid*32], (unsigned)(t+1), __ATOMIC_RELEASE, __HIP_MEMORY_SCOPE_AGENT);
      acc0x = f32x4{0.f,0.f,0.f,0.f};
      if (t+1 < NT){
        const ushort* xt = hlnb + (size_t)(t+1)*BATCH*NFP;
        #pragma unroll
        for (int kt=0; kt<9; kt++){
          short8 a = *(const short8*)(xt + arow*NFP + kt*32 + kg*8);
          short8 b = *(const short8*)(wb0 + kt*32 + kg*8);
          acc0x = __builtin_amdgcn_mfma_f32_16x16x32_bf16(a, b, acc0x, 0, 0, 0);
        }
      }
      if (wave == 0){
        unsigned tgt = (unsigned)(t+1);
        while (true){
          unsigned v = __hip_atomic_load(&flagsA[lane*32], __ATOMIC_RELAXED, __HIP_MEMORY_SCOPE_AGENT);
          if (__all(v >= tgt)) break;
          __builtin_amdgcn_s_sleep(1);
        }
        if (lbid == 0 && lane == 0)
          __hip_atomic_store(epoch, (unsigned)(t+1), __ATOMIC_RELAXED, __HIP_MEMORY_SCOPE_AGENT);
        (void)__hip_atomic_load(&flagsA[lane*32], __ATOMIC_ACQUIRE, __HIP_MEMORY_SCOPE_AGENT);
      }
      asm volatile("" ::: "memory");
      __syncthreads();
    }
    return;
  }

  // ================= worker role =================
  const int w = ((bid >> 3) * 6) + (r8 - 2);   // 0..191
  for (int c = 0; c < NCHUNK; ++c){
    int tcc = (c == NCHUNK-1) ? (NT - c*TC) : TC;
    int tb0 = c*TC - 4;
    unsigned need = (unsigned)(c*TC + tcc + 1);
    if (tid == 0){
      while (__hip_atomic_load(epoch, __ATOMIC_RELAXED, __HIP_MEMORY_SCOPE_AGENT) < need)
        __builtin_amdgcn_s_sleep(32);
      (void)__hip_atomic_load(epoch, __ATOMIC_ACQUIRE, __HIP_MEMORY_SCOPE_AGENT);
    }
    __syncthreads();
    // P0: chunk STFT
    for (int i = w; i < 36*BATCH; i += NWORK)
      dev_stft_frame(x, tw, spR, spI, tb0, i % 36, i / 36, fr);
    {
      unsigned* d0 = done + (c*3+0)*32;
      __syncthreads();
      if (tid == 0){
        __hip_atomic_fetch_add(d0, 1u, __ATOMIC_RELEASE, __HIP_MEMORY_SCOPE_AGENT);
        while (__hip_atomic_load(d0, __ATOMIC_RELAXED, __HIP_MEMORY_SCOPE_AGENT) < NWORK)
          __builtin_amdgcn_s_sleep(4);
        (void)__hip_atomic_load(d0, __ATOMIC_ACQUIRE, __HIP_MEMORY_SCOPE_AGENT);
      }
      __syncthreads();
    }
    // P1: proj GEMM
    {
      int gy = (tcc*BATCH)/64;
      int ntask = 81*gy;
      const ushort* A = h1hist + ((size_t)(c*TC)+1)*BATCH*HID;
      for (int i = w; i < ntask; i += NWORK)
        dev_gemm_tile(A, projWb, projb, prch, tcc*BATCH, PROJN, i % 81, i / 81);
      unsigned* d1 = done + (c*3+1)*32;
      __syncthreads();
      if (tid == 0){
        __hip_atomic_fetch_add(d1, 1u, __ATOMIC_RELEASE, __HIP_MEMORY_SCOPE_AGENT);
        while (__hip_atomic_load(d1, __ATOMIC_RELAXED, __HIP_MEMORY_SCOPE_AGENT) < NWORK)
          __builtin_amdgcn_s_sleep(4);
        (void)__hip_atomic_load(d1, __ATOMIC_ACQUIRE, __HIP_MEMORY_SCOPE_AGENT);
      }
      __syncthreads();
    }
    // P2: filter + iFFT + OLA
    {
      for (int i = w; i < tcc*64; i += NWORK)
        dev_ifused_task(prch, spR, spI, tw, out, tb0, i, reb, imb);
      unsigned* d2 = done + (c*3+2)*32;
      __syncthreads();
      if (tid == 0){
        __hip_atomic_fetch_add(d2, 1u, __ATOMIC_RELEASE, __HIP_MEMORY_SCOPE_AGENT);
        while (__hip_atomic_load(d2, __ATOMIC_RELAXED, __HIP_MEMORY_SCOPE_AGENT) < NWORK)
          __builtin_amdgcn_s_sleep(4);
        (void)__hip_atomic_load(d2, __ATOMIC_ACQUIRE, __HIP_MEMORY_SCOPE_AGENT);
      }
      __syncthreads();
    }
  }
  // ---- normalize ----
  for (size_t i = (size_t)w*256 + tid; i < (size_t)64*LEN; i += (size_t)NWORK*256){
    int m = (int)(i % LEN) & 255;
    float cm = tw[m];
    float w1 = 0.5f - 0.5f*cm;
    float w2 = 0.5f + 0.5f*cm;
    out[i] = out[i] / (w1*w1 + w2*w2);
  }
}

extern "C" void kernel_launch(void* const* d_in, const int* in_sizes, int n_in,
                              void* d_out, int out_size, void* d_ws, size_t ws_size,
                              hipStream_t stream){
  const float* x     = (const float*)d_in[0];
  const float* ln_g  = (const float*)d_in[1];
  const float* ln_b  = (const float*)d_in[2];
  const float* Wih0  = (const float*)d_in[3];
  const float* Whh0  = (const float*)d_in[4];
  const float* bih0  = (const float*)d_in[5];
  const float* bhh0  = (const float*)d_in[6];
  const float* Wih1  = (const float*)d_in[7];
  const float* Whh1  = (const float*)d_in[8];
  const float* bih1  = (const float*)d_in[9];
  const float* bhh1  = (const float*)d_in[10];
  const float* projW = (const float*)d_in[11];
  const float* projb = (const float*)d_in[12];

  char* base = (char*)d_ws;
  size_t off = 0;
  auto carve = [&](size_t bytes)->char*{
    char* p = base + off;
    off += (bytes + 255) & ~(size_t)255;
    return p;
  };
  float*  tw     = (float*) carve(1024*4);
  ushort* hlnb   = (ushort*)carve((size_t)NT*BATCH*NFP*2);
  ushort* W0     = (ushort*)carve((size_t)2048*K0*2);
  ushort* W1     = (ushort*)carve((size_t)2048*K1*2);
  float*  b0c    = (float*) carve(2048*4);
  float*  b1c    = (float*) carve(2048*4);
  ushort* projWb = (ushort*)carve((size_t)PROJN*HID*2);
  size_t zoff0 = off;
  ushort* h0b    = (ushort*)carve((size_t)2*BATCH*HID*2);
  ushort* h1b    = (ushort*)carve((size_t)2*BATCH*HID*2);
  unsigned* flagsA = (unsigned*)carve(NLSTM*32*4);
  unsigned* epoch  = (unsigned*)carve(128);
  unsigned* done   = (unsigned*)carve(NCHUNK*3*32*4);
  size_t zlen = off - zoff0;
  ushort* h1hist = (ushort*)carve((size_t)(NT+1)*BATCH*HID*2);
  float*  spR    = (float*) carve((size_t)BATCH*NF*36*4);
  float*  spI    = (float*) carve((size_t)BATCH*NF*36*4);
  float*  prch   = (float*) carve((size_t)TC*BATCH*PROJN*4);

  k_setup<<<4096, 256, 0, stream>>>(tw, (int*)(base + zoff0), (int)(zlen/4),
                                    (float*)h1hist, BATCH*HID/2,
                                    (float*)d_out, out_size,
                                    Wih0, Whh0, bih0, bhh0, Wih1, Whh1, bih1, bhh1,
                                    projW, W0, W1, b0c, b1c, projWb);
  k_stftln<<<BATCH*NT, 256, 0, stream>>>(x, tw, ln_g, ln_b, hlnb);

  {
    float* outp = (float*)d_out;
    void* args[] = { (void*)&hlnb, (void*)&W0, (void*)&W1, (void*)&b0c, (void*)&b1c,
                     (void*)&h0b, (void*)&h1b, (void*)&h1hist,
                     (void*)&flagsA, (void*)&epoch, (void*)&done,
                     (void*)&x, (void*)&tw, (void*)&projWb, (void*)&projb,
                     (void*)&spR, (void*)&spI, (void*)&prch, (void*)&outp };
    hipLaunchCooperativeKernel(reinterpret_cast<void*>(k_mega), dim3(NBLKT), dim3(256),
                               args, 0, stream);
  }
}

// Round 17
// 9246.484 us; speedup vs baseline: 1.3991x; 1.3991x over previous
//
#include <hip/hip_runtime.h>
#include <hip/hip_cooperative_groups.h>
#include <math.h>

#define BATCH 32
#define LEN   160000
#define NFFT  512
#define NT    626
#define NF    257
#define NFP   288          // NF padded to 9*32
#define HID   512
#define PROJN 5140
#define TC    32
#define NCHUNK 20
#define K0    800          // NFP + HID
#define K1    1024         // HID + HID
#define NLSTM 64           // LSTM blocks
#define NWORK 192          // worker blocks
#define NBLKT 256          // total blocks

typedef unsigned short ushort;
typedef __attribute__((ext_vector_type(8))) short short8;
typedef __attribute__((ext_vector_type(4))) float f32x4;

__device__ __forceinline__ float sigm(float x){ return 1.0f/(1.0f+expf(-x)); }
__device__ __forceinline__ ushort f2bf(float f){
  union{float f;unsigned u;} v; v.f=f;
  unsigned r = v.u + 0x7fffu + ((v.u>>16)&1u);
  return (ushort)(r>>16);
}

// ---------------- merged setup ----------------
__global__ __launch_bounds__(256) void k_setup(float* tw, int* zr, int nz,
                                               float* h1slot0, int nh1s,
                                               float* outz, int nout,
                                               const float* __restrict__ Wih0, const float* __restrict__ Whh0,
                                               const float* __restrict__ bih0, const float* __restrict__ bhh0,
                                               const float* __restrict__ Wih1, const float* __restrict__ Whh1,
                                               const float* __restrict__ bih1, const float* __restrict__ bhh1,
                                               const float* __restrict__ projW,
                                               ushort* __restrict__ W0, ushort* __restrict__ W1,
                                               float* __restrict__ b0c, float* __restrict__ b1c,
                                               ushort* __restrict__ projWb){
  const int gsz = gridDim.x*256;
  int gid = blockIdx.x*256 + threadIdx.x;
  if (gid < 512){
    float ang = 6.28318530717958647692f * (float)gid / 512.0f;
    tw[gid]     = cosf(ang);
    tw[512+gid] = sinf(ang);
  }
  for (int j = gid; j < nz; j += gsz) zr[j] = 0;
  for (int j = gid; j < nh1s; j += gsz) h1slot0[j] = 0.f;
  for (int j = gid; j < nout; j += gsz) outz[j] = 0.f;
  const int n0 = 2048*K0, n1 = 2048*K1, n2 = PROJN*HID;
  for (int i = gid; i < n0 + n1 + 4096 + n2; i += gsz){
    if (i < n0){
      int r = i / K0, c = i - r*K0;
      float v = (c < 257) ? Wih0[(size_t)r*257 + c] : (c < NFP ? 0.f : Whh0[(size_t)r*512 + (c-NFP)]);
      W0[i] = f2bf(v);
    } else if (i < n0 + n1){
      int j = i - n0;
      int r = j / K1, c = j - r*K1;
      float v = (c < 512) ? Wih1[(size_t)r*512 + c] : Whh1[(size_t)r*512 + (c-512)];
      W1[j] = f2bf(v);
    } else if (i < n0 + n1 + 4096){
      int j = i - n0 - n1;
      if (j < 2048) b0c[j] = bih0[j] + bhh0[j];
      else          b1c[j-2048] = bih1[j-2048] + bhh1[j-2048];
    } else {
      int j = i - n0 - n1 - 4096;
      projWb[j] = f2bf(projW[j]);
    }
  }
}

// ---------------- fused STFT + mag^0.5 + LayerNorm ----------------
__global__ __launch_bounds__(256) void k_stftln(const float* __restrict__ x, const float* __restrict__ tw,
                                                const float* __restrict__ g, const float* __restrict__ be,
                                                ushort* __restrict__ hlnb){
  int b = blockIdx.x / NT;
  int t = blockIdx.x % NT;
  __shared__ float fr[NFFT], mg[NF];
  __shared__ float red[16];
  const float* xb = x + (size_t)b*LEN;
  for (int n = threadIdx.x; n < NFFT; n += 256){
    int j = t*256 + n - 256;
    if (j < 0) j = -j;
    else if (j >= LEN) j = 2*LEN - 2 - j;
    fr[n] = xb[j] * (0.5f - 0.5f*tw[n]);
  }
  __syncthreads();
  float v=0.f, v2=0.f;
  for (int f = threadIdx.x; f < NF; f += 256){
    float c4 = tw[(4*f)&511], s4 = tw[512+((4*f)&511)];
    float cr0=1.f,            si0=0.f;
    float cr1=tw[f&511],      si1=tw[512+(f&511)];
    float cr2=tw[(2*f)&511],  si2=tw[512+((2*f)&511)];
    float cr3=tw[(3*f)&511],  si3=tw[512+((3*f)&511)];
    float ar0=0.f,ai0=0.f,ar1=0.f,ai1=0.f,ar2=0.f,ai2=0.f,ar3=0.f,ai3=0.f;
    #pragma unroll 4
    for (int n = 0; n < NFFT; n += 4){
      ar0 += fr[n  ]*cr0; ai0 -= fr[n  ]*si0;
      ar1 += fr[n+1]*cr1; ai1 -= fr[n+1]*si1;
      ar2 += fr[n+2]*cr2; ai2 -= fr[n+2]*si2;
      ar3 += fr[n+3]*cr3; ai3 -= fr[n+3]*si3;
      float tc, ts;
      tc = cr0*c4 - si0*s4; ts = cr0*s4 + si0*c4; cr0=tc; si0=ts;
      tc = cr1*c4 - si1*s4; ts = cr1*s4 + si1*c4; cr1=tc; si1=ts;
      tc = cr2*c4 - si2*s4; ts = cr2*s4 + si2*c4; cr2=tc; si2=ts;
      tc = cr3*c4 - si3*s4; ts = cr3*s4 + si3*c4; cr3=tc; si3=ts;
    }
    float ar = (ar0+ar1)+(ar2+ar3);
    float ai = (ai0+ai1)+(ai2+ai3);
    float m = sqrtf(sqrtf(ar*ar + ai*ai));
    mg[f]=m; v+=m; v2+=m*m;
  }
  for (int off=32; off; off>>=1){ v += __shfl_down(v,off); v2 += __shfl_down(v2,off); }
  int w = threadIdx.x >> 6;
  if ((threadIdx.x & 63)==0){ red[w]=v; red[8+w]=v2; }
  __syncthreads();
  if (threadIdx.x==0){
    float s  = red[0]+red[1]+red[2]+red[3];
    float s2 = red[8]+red[9]+red[10]+red[11];
    float mu = s/(float)NF;
    red[4]=mu;
    red[5]=rsqrtf(s2/(float)NF - mu*mu + 1e-5f);
  }
  __syncthreads();
  float mu=red[4], rs=red[5];
  size_t ob = ((size_t)t*BATCH + b)*NFP;
  for (int f=threadIdx.x; f<NFP; f+=256){
    float val = 0.f;
    if (f < NF) val = (mg[f]-mu)*rs*g[f] + be[f];
    hlnb[ob+f] = f2bf(val);
  }
}

// ================= worker device functions =================
__device__ void dev_stft_frame(const float* __restrict__ x, const float* __restrict__ tw,
                               float* __restrict__ spR, float* __restrict__ spI,
                               int tb0, int tt, int b, float* fr){
  int t = tb0 + tt;
  int tid = threadIdx.x;
  if (t < 0 || t >= NT){
    for (int f = tid; f < NF; f += 256){
      size_t o = ((size_t)b*NF + f)*36 + tt;
      spR[o]=0.f; spI[o]=0.f;
    }
    return;
  }
  const float* xb = x + (size_t)b*LEN;
  for (int n = tid; n < NFFT; n += 256){
    int j = t*256 + n - 256;
    if (j < 0) j = -j;
    else if (j >= LEN) j = 2*LEN - 2 - j;
    fr[n] = xb[j] * (0.5f - 0.5f*tw[n]);
  }
  __syncthreads();
  for (int f = tid; f < NF; f += 256){
    float c4 = tw[(4*f)&511], s4 = tw[512+((4*f)&511)];
    float cr0=1.f,            si0=0.f;
    float cr1=tw[f&511],      si1=tw[512+(f&511)];
    float cr2=tw[(2*f)&511],  si2=tw[512+((2*f)&511)];
    float cr3=tw[(3*f)&511],  si3=tw[512+((3*f)&511)];
    float ar0=0.f,ai0=0.f,ar1=0.f,ai1=0.f,ar2=0.f,ai2=0.f,ar3=0.f,ai3=0.f;
    #pragma unroll 4
    for (int n = 0; n < NFFT; n += 4){
      ar0 += fr[n  ]*cr0; ai0 -= fr[n  ]*si0;
      ar1 += fr[n+1]*cr1; ai1 -= fr[n+1]*si1;
      ar2 += fr[n+2]*cr2; ai2 -= fr[n+2]*si2;
      ar3 += fr[n+3]*cr3; ai3 -= fr[n+3]*si3;
      float tc, ts;
      tc = cr0*c4 - si0*s4; ts = cr0*s4 + si0*c4; cr0=tc; si0=ts;
      tc = cr1*c4 - si1*s4; ts = cr1*s4 + si1*c4; cr1=tc; si1=ts;
      tc = cr2*c4 - si2*s4; ts = cr2*s4 + si2*c4; cr2=tc; si2=ts;
      tc = cr3*c4 - si3*s4; ts = cr3*s4 + si3*c4; cr3=tc; si3=ts;
    }
    size_t o = ((size_t)b*NF + f)*36 + tt;
    spR[o] = (ar0+ar1)+(ar2+ar3);
    spI[o] = (ai0+ai1)+(ai2+ai3);
  }
  __syncthreads();
}

__device__ void dev_gemm_tile(const ushort* __restrict__ A, const ushort* __restrict__ Bb,
                              const float* __restrict__ bias, float* __restrict__ C,
                              int M, int N, int bx, int by){
  int bm = by*64, bn = bx*64;
  int wave = threadIdx.x >> 6, lane = threadIdx.x & 63;
  int wm = wave >> 1, wn = wave & 1;
  int col = lane & 15, kg = lane >> 4;
  f32x4 acc00={0.f,0.f,0.f,0.f}, acc01=acc00, acc10=acc00, acc11=acc00;
  const ushort* Ap = A + (size_t)(bm + wm*32)*512;
  int nr0 = bn + wn*32 + col;
  int nr1 = nr0 + 16;
  const ushort* Bp0 = Bb + (size_t)((nr0<N)?nr0:0)*512;
  const ushort* Bp1 = Bb + (size_t)((nr1<N)?nr1:0)*512;
  #pragma unroll 4
  for (int k0=0; k0<512; k0+=32){
    short8 a0 = *(const short8*)(Ap + (size_t)col*512 + k0 + kg*8);
    short8 a1 = *(const short8*)(Ap + (size_t)(16+col)*512 + k0 + kg*8);
    short8 b0 = *(const short8*)(Bp0 + k0 + kg*8);
    short8 b1 = *(const short8*)(Bp1 + k0 + kg*8);
    acc00 = __builtin_amdgcn_mfma_f32_16x16x32_bf16(a0, b0, acc00, 0, 0, 0);
    acc01 = __builtin_amdgcn_mfma_f32_16x16x32_bf16(a0, b1, acc01, 0, 0, 0);
    acc10 = __builtin_amdgcn_mfma_f32_16x16x32_bf16(a1, b0, acc10, 0, 0, 0);
    acc11 = __builtin_amdgcn_mfma_f32_16x16x32_bf16(a1, b1, acc11, 0, 0, 0);
  }
  #define STORE_ACC(ACC, MI, NI) { \
    int n = bn + wn*32 + (NI)*16 + col; \
    if (n < N){ \
      float bv = bias[n]; \
      _Pragma("unroll") \
      for (int j=0;j<4;j++){ \
        int m = bm + wm*32 + (MI)*16 + kg*4 + j; \
        C[(size_t)m*N + n] = tanhf(ACC[j] + bv); \
      } \
    } }
  STORE_ACC(acc00, 0, 0)
  STORE_ACC(acc01, 0, 1)
  STORE_ACC(acc10, 1, 0)
  STORE_ACC(acc11, 1, 1)
  #undef STORE_ACC
}

__device__ void dev_ifused_task(const float* __restrict__ prch,
    const float* __restrict__ spR, const float* __restrict__ spI,
    const float* __restrict__ tw, float* __restrict__ out, int tb0, int task,
    float* reb, float* imb){
  int tl = task >> 6;
  int b  = (task >> 1) & 31;
  int s  = task & 1;
  int tau = tb0 + 4 + tl;
  int tid = threadIdx.x;
  const float* p = prch + ((size_t)tl*BATCH + b)*PROJN;
  for (int f=tid; f<NF; f+=256){
    float ar=0.f, ai=0.f;
    size_t so = ((size_t)b*NF + f)*36;
    #pragma unroll
    for (int d=0; d<5; d++){
      int ts = tb0 + tl + d;
      if (ts >= 0){
        float sr=spR[so + tl + d], si=spI[so + tl + d];
        float cr=p[d*514 + s*257 + f];
        float ci=p[2570 + d*514 + s*257 + f];
        ar += sr*cr - si*ci;
        ai += sr*ci + si*cr;
      }
    }
    reb[f]=ar; imb[f]=ai;
  }
  __syncthreads();
  float* ob = out + (size_t)(b*2+s)*LEN;
  for (int n=tid; n<NFFT; n+=256){
    float c4 = tw[(4*n)&511], s4 = tw[512+((4*n)&511)];
    float crA=tw[n&511],     siA=tw[512+(n&511)];
    float crB=tw[(2*n)&511], siB=tw[512+((2*n)&511)];
    float crC=tw[(3*n)&511], siC=tw[512+((3*n)&511)];
    float crD=c4,            siD=s4;
    float a0=0.f,a1=0.f,a2=0.f,a3=0.f;
    #pragma unroll 4
    for (int m=0; m<63; m++){
      int k = 4*m+1;
      a0 += reb[k  ]*crA - imb[k  ]*siA;
      a1 += reb[k+1]*crB - imb[k+1]*siB;
      a2 += reb[k+2]*crC - imb[k+2]*siC;
      a3 += reb[k+3]*crD - imb[k+3]*siD;
      float tc, ts;
      tc = crA*c4 - siA*s4; ts = crA*s4 + siA*c4; crA=tc; siA=ts;
      tc = crB*c4 - siB*s4; ts = crB*s4 + siB*c4; crB=tc; siB=ts;
      tc = crC*c4 - siC*s4; ts = crC*s4 + siC*c4; crC=tc; siC=ts;
      tc = crD*c4 - siD*s4; ts = crD*s4 + siD*c4; crD=tc; siD=ts;
    }
    a0 += reb[253]*crA - imb[253]*siA;
    a1 += reb[254]*crB - imb[254]*siB;
    a2 += reb[255]*crC - imb[255]*siC;
    float acc = reb[0] + ((n&1) ? -reb[256] : reb[256]) + 2.f*((a0+a1)+(a2+a3));
    int pos = tau*256 - 256 + n;
    if (pos >= 0 && pos < LEN)
      atomicAdd(ob + pos, acc * (1.0f/512.0f) * (0.5f - 0.5f*tw[n&511]));
  }
  __syncthreads();
}

// ================= persistent mega-kernel (r14/r12 structure — measured best) =================
__global__ __launch_bounds__(256, 1) void k_mega(const ushort* __restrict__ hlnb,
    const ushort* __restrict__ W0g, const ushort* __restrict__ W1g,
    const float* __restrict__ b0c, const float* __restrict__ b1c,
    ushort* __restrict__ h0b, ushort* __restrict__ h1b, ushort* __restrict__ h1hist,
    unsigned* __restrict__ flagsA, unsigned* __restrict__ epoch, unsigned* __restrict__ done,
    const float* __restrict__ x, const float* __restrict__ tw,
    const ushort* __restrict__ projWb, const float* __restrict__ projb,
    float* __restrict__ spR, float* __restrict__ spI, float* __restrict__ prch,
    float* __restrict__ out){
  __shared__ ushort Wlds0[32*808];
  __shared__ ushort Wlds1[32*1032];
  __shared__ float pc0[32][33];
  __shared__ float pc1[32][33];
  __shared__ float fr[NFFT];
  __shared__ float reb[NF], imb[NF];

  const int tid  = threadIdx.x;
  const int bid  = blockIdx.x;

  if (bid < NLSTM){
    // ================= LSTM role (r6 canonical) =================
    const int u0   = bid << 3;
    const int wave = tid >> 6;
    const int lane = tid & 63;
    const int col  = lane & 15;
    const int kg   = lane >> 4;
    const int mh   = wave & 1;
    const int nh   = wave >> 1;
    const int arow = (mh<<4) + col;
    const int nlo  = (nh<<4) + col;

    for (int v = tid; v < 3200; v += 256){
      int r = v/100, c8 = v - r*100;
      int grow = ((r>>3)<<9) + u0 + (r&7);
      *(short8*)&Wlds0[r*808 + c8*8] = *(const short8*)(W0g + (size_t)grow*K0 + c8*8);
    }
    for (int v = tid; v < 4096; v += 256){
      int r = v>>7, c8 = v&127;
      int grow = ((r>>3)<<9) + u0 + (r&7);
      *(short8*)&Wlds1[r*1032 + c8*8] = *(const short8*)(W1g + (size_t)grow*K1 + c8*8);
    }
    const int bb = tid & 31;
    const int ul = tid >> 5;
    const int u  = u0 + ul;
    float bc0r[4], bc1r[4];
    #pragma unroll
    for (int g=0; g<4; g++){ bc0r[g] = b0c[(g<<9)+u]; bc1r[g] = b1c[(g<<9)+u]; }
    float c0r = 0.f, c1r = 0.f;
    const ushort* wb0 = &Wlds0[nlo*808];
    const ushort* wb1 = &Wlds1[nlo*1032];
    __syncthreads();

    f32x4 acc0x = {0.f,0.f,0.f,0.f};
    {
      const ushort* xt = hlnb;
      #pragma unroll
      for (int kt=0; kt<9; kt++){
        short8 a = *(const short8*)(xt + arow*NFP + kt*32 + kg*8);
        short8 b = *(const short8*)(wb0 + kt*32 + kg*8);
        acc0x = __builtin_amdgcn_mfma_f32_16x16x32_bf16(a, b, acc0x, 0, 0, 0);
      }
    }

    for (int t = 0; t <= NT; ++t){
      const ushort* h0p = h0b + (size_t)((t-1)&1)*(BATCH*HID);
      f32x4 acc0 = acc0x;
      f32x4 acc1 = {0.f,0.f,0.f,0.f};
      if (t >= 1){
        const ushort* h1p = h1b + (size_t)((t-2)&1)*(BATCH*HID);
        #pragma unroll
        for (int kt=0; kt<16; kt++){
          short8 a = *(const short8*)(h0p + arow*HID + kt*32 + kg*8);
          short8 b = *(const short8*)(wb1 + kt*32 + kg*8);
          acc1 = __builtin_amdgcn_mfma_f32_16x16x32_bf16(a, b, acc1, 0, 0, 0);
        }
        #pragma unroll
        for (int kt=0; kt<16; kt++){
          short8 a = *(const short8*)(h1p + arow*HID + kt*32 + kg*8);
          short8 b = *(const short8*)(wb1 + 512 + kt*32 + kg*8);
          acc1 = __builtin_amdgcn_mfma_f32_16x16x32_bf16(a, b, acc1, 0, 0, 0);
        }
      }
      if (t < NT){
        #pragma unroll
        for (int kt=0; kt<16; kt++){
          short8 a = *(const short8*)(h0p + arow*HID + kt*32 + kg*8);
          short8 b = *(const short8*)(wb0 + 288 + kt*32 + kg*8);
          acc0 = __builtin_amdgcn_mfma_f32_16x16x32_bf16(a, b, acc0, 0, 0, 0);
        }
      }
      if (t < NT){
        #pragma unroll
        for (int j=0;j<4;j++) pc0[(mh<<4)+(kg<<2)+j][nlo] = acc0[j];
      }
      if (t >= 1){
        #pragma unroll
        for (int j=0;j<4;j++) pc1[(mh<<4)+(kg<<2)+j][nlo] = acc1[j];
      }
      __syncthreads();
      if (t < NT){
        float p0 = pc0[bb][0*8+ul] + bc0r[0];
        float p1 = pc0[bb][1*8+ul] + bc0r[1];
        float p2 = pc0[bb][2*8+ul] + bc0r[2];
        float p3 = pc0[bb][3*8+ul] + bc0r[3];
        float cn = sigm(p1)*c0r + sigm(p0)*tanhf(p2);
        float hn = sigm(p3)*tanhf(cn);
        c0r = cn;
        h0b[(size_t)(t&1)*(BATCH*HID) + bb*HID + u] = f2bf(hn);
      }
      if (t >= 1){
        float p0 = pc1[bb][0*8+ul] + bc1r[0];
        float p1 = pc1[bb][1*8+ul] + bc1r[1];
        float p2 = pc1[bb][2*8+ul] + bc1r[2];
        float p3 = pc1[bb][3*8+ul] + bc1r[3];
        float cn = sigm(p1)*c1r + sigm(p0)*tanhf(p2);
        float hn = sigm(p3)*tanhf(cn);
        c1r = cn;
        ushort hb = f2bf(hn);
        h1b[(size_t)((t-1)&1)*(BATCH*HID) + bb*HID + u] = hb;
        __builtin_nontemporal_store(hb, h1hist + (size_t)t*(BATCH*HID) + bb*HID + u);
      }
      __syncthreads();                     // drain stores (vmcnt0)
      if (tid == 0)
        __hip_atomic_store(&flagsA[bid*32], (unsigned)(t+1), __ATOMIC_RELEASE, __HIP_MEMORY_SCOPE_AGENT);
      acc0x = f32x4{0.f,0.f,0.f,0.f};
      if (t+1 < NT){
        const ushort* xt = hlnb + (size_t)(t+1)*BATCH*NFP;
        #pragma unroll
        for (int kt=0; kt<9; kt++){
          short8 a = *(const short8*)(xt + arow*NFP + kt*32 + kg*8);
          short8 b = *(const short8*)(wb0 + kt*32 + kg*8);
          acc0x = __builtin_amdgcn_mfma_f32_16x16x32_bf16(a, b, acc0x, 0, 0, 0);
        }
      }
      if (wave == 0){
        unsigned tgt = (unsigned)(t+1);
        while (true){
          unsigned v = __hip_atomic_load(&flagsA[lane*32], __ATOMIC_RELAXED, __HIP_MEMORY_SCOPE_AGENT);
          if (__all(v >= tgt)) break;
          __builtin_amdgcn_s_sleep(1);
        }
        if (bid == 0 && lane == 0)
          __hip_atomic_store(epoch, (unsigned)(t+1), __ATOMIC_RELAXED, __HIP_MEMORY_SCOPE_AGENT);
        (void)__hip_atomic_load(&flagsA[lane*32], __ATOMIC_ACQUIRE, __HIP_MEMORY_SCOPE_AGENT);
      }
      asm volatile("" ::: "memory");
      __syncthreads();
    }
    return;
  }

  // ================= worker role =================
  const int w = bid - NLSTM;
  for (int c = 0; c < NCHUNK; ++c){
    int tcc = (c == NCHUNK-1) ? (NT - c*TC) : TC;
    int tb0 = c*TC - 4;
    unsigned need = (unsigned)(c*TC + tcc + 1);
    if (tid == 0){
      while (__hip_atomic_load(epoch, __ATOMIC_RELAXED, __HIP_MEMORY_SCOPE_AGENT) < need)
        __builtin_amdgcn_s_sleep(32);
      (void)__hip_atomic_load(epoch, __ATOMIC_ACQUIRE, __HIP_MEMORY_SCOPE_AGENT);
    }
    __syncthreads();
    // P0: chunk STFT
    for (int i = w; i < 36*BATCH; i += NWORK)
      dev_stft_frame(x, tw, spR, spI, tb0, i % 36, i / 36, fr);
    {
      unsigned* d0 = done + (c*3+0)*32;
      __syncthreads();
      if (tid == 0){
        __hip_atomic_fetch_add(d0, 1u, __ATOMIC_RELEASE, __HIP_MEMORY_SCOPE_AGENT);
        while (__hip_atomic_load(d0, __ATOMIC_RELAXED, __HIP_MEMORY_SCOPE_AGENT) < NWORK)
          __builtin_amdgcn_s_sleep(4);
        (void)__hip_atomic_load(d0, __ATOMIC_ACQUIRE, __HIP_MEMORY_SCOPE_AGENT);
      }
      __syncthreads();
    }
    // P1: proj GEMM
    {
      int gy = (tcc*BATCH)/64;
      int ntask = 81*gy;
      const ushort* A = h1hist + ((size_t)(c*TC)+1)*BATCH*HID;
      for (int i = w; i < ntask; i += NWORK)
        dev_gemm_tile(A, projWb, projb, prch, tcc*BATCH, PROJN, i % 81, i / 81);
      unsigned* d1 = done + (c*3+1)*32;
      __syncthreads();
      if (tid == 0){
        __hip_atomic_fetch_add(d1, 1u, __ATOMIC_RELEASE, __HIP_MEMORY_SCOPE_AGENT);
        while (__hip_atomic_load(d1, __ATOMIC_RELAXED, __HIP_MEMORY_SCOPE_AGENT) < NWORK)
          __builtin_amdgcn_s_sleep(4);
        (void)__hip_atomic_load(d1, __ATOMIC_ACQUIRE, __HIP_MEMORY_SCOPE_AGENT);
      }
      __syncthreads();
    }
    // P2: filter + iFFT + OLA
    {
      for (int i = w; i < tcc*64; i += NWORK)
        dev_ifused_task(prch, spR, spI, tw, out, tb0, i, reb, imb);
      unsigned* d2 = done + (c*3+2)*32;
      __syncthreads();
      if (tid == 0){
        __hip_atomic_fetch_add(d2, 1u, __ATOMIC_RELEASE, __HIP_MEMORY_SCOPE_AGENT);
        while (__hip_atomic_load(d2, __ATOMIC_RELAXED, __HIP_MEMORY_SCOPE_AGENT) < NWORK)
          __builtin_amdgcn_s_sleep(4);
        (void)__hip_atomic_load(d2, __ATOMIC_ACQUIRE, __HIP_MEMORY_SCOPE_AGENT);
      }
      __syncthreads();
    }
  }
  // ---- normalize ----
  for (size_t i = (size_t)w*256 + tid; i < (size_t)64*LEN; i += (size_t)NWORK*256){
    int m = (int)(i % LEN) & 255;
    float cm = tw[m];
    float w1 = 0.5f - 0.5f*cm;
    float w2 = 0.5f + 0.5f*cm;
    out[i] = out[i] / (w1*w1 + w2*w2);
  }
}

extern "C" void kernel_launch(void* const* d_in, const int* in_sizes, int n_in,
                              void* d_out, int out_size, void* d_ws, size_t ws_size,
                              hipStream_t stream){
  const float* x     = (const float*)d_in[0];
  const float* ln_g  = (const float*)d_in[1];
  const float* ln_b  = (const float*)d_in[2];
  const float* Wih0  = (const float*)d_in[3];
  const float* Whh0  = (const float*)d_in[4];
  const float* bih0  = (const float*)d_in[5];
  const float* bhh0  = (const float*)d_in[6];
  const float* Wih1  = (const float*)d_in[7];
  const float* Whh1  = (const float*)d_in[8];
  const float* bih1  = (const float*)d_in[9];
  const float* bhh1  = (const float*)d_in[10];
  const float* projW = (const float*)d_in[11];
  const float* projb = (const float*)d_in[12];

  char* base = (char*)d_ws;
  size_t off = 0;
  auto carve = [&](size_t bytes)->char*{
    char* p = base + off;
    off += (bytes + 255) & ~(size_t)255;
    return p;
  };
  float*  tw     = (float*) carve(1024*4);
  ushort* hlnb   = (ushort*)carve((size_t)NT*BATCH*NFP*2);
  ushort* W0     = (ushort*)carve((size_t)2048*K0*2);
  ushort* W1     = (ushort*)carve((size_t)2048*K1*2);
  float*  b0c    = (float*) carve(2048*4);
  float*  b1c    = (float*) carve(2048*4);
  ushort* projWb = (ushort*)carve((size_t)PROJN*HID*2);
  size_t zoff0 = off;
  ushort* h0b    = (ushort*)carve((size_t)2*BATCH*HID*2);
  ushort* h1b    = (ushort*)carve((size_t)2*BATCH*HID*2);
  unsigned* flagsA = (unsigned*)carve(NLSTM*32*4);
  unsigned* epoch  = (unsigned*)carve(128);
  unsigned* done   = (unsigned*)carve(NCHUNK*3*32*4);
  size_t zlen = off - zoff0;
  ushort* h1hist = (ushort*)carve((size_t)(NT+1)*BATCH*HID*2);
  float*  spR    = (float*) carve((size_t)BATCH*NF*36*4);
  float*  spI    = (float*) carve((size_t)BATCH*NF*36*4);
  float*  prch   = (float*) carve((size_t)TC*BATCH*PROJN*4);

  k_setup<<<4096, 256, 0, stream>>>(tw, (int*)(base + zoff0), (int)(zlen/4),
                                    (float*)h1hist, BATCH*HID/2,
                                    (float*)d_out, out_size,
                                    Wih0, Whh0, bih0, bhh0, Wih1, Whh1, bih1, bhh1,
                                    projW, W0, W1, b0c, b1c, projWb);
  k_stftln<<<BATCH*NT, 256, 0, stream>>>(x, tw, ln_g, ln_b, hlnb);

  {
    float* outp = (float*)d_out;
    void* args[] = { (void*)&hlnb, (void*)&W0, (void*)&W1, (void*)&b0c, (void*)&b1c,
                     (void*)&h0b, (void*)&h1b, (void*)&h1hist,
                     (void*)&flagsA, (void*)&epoch, (void*)&done,
                     (void*)&x, (void*)&tw, (void*)&projWb, (void*)&projb,
                     (void*)&spR, (void*)&spI, (void*)&prch, (void*)&outp };
    hipLaunchCooperativeKernel(reinterpret_cast<void*>(k_mega), dim3(NBLKT), dim3(256),
                               args, 0, stream);
  }
}